// Round 1
// baseline (773.013 us; speedup 1.0000x reference)
//
#include <hip/hip_runtime.h>

// SSIM(x, y) over (C=8, H=2048, W=2048) fp32, 11x11 separable Gaussian,
// zero padding, output = scalar mean.
//
// Separable decomposition: kernel k[i][j] = wc[i] * wr[j] with
//   wr[j] = k[5][j], wc[i] = k[i][5] / k[5][5]   (exact up to fp rounding)
//
// Fused single kernel: per block, tile TH x TW of one channel.
//   Phase A: stage x,y tile + 5-halo into LDS (zero-padded).
//   Phase B: horizontal 11-tap conv of {x, y, xx, yy, xy} -> 5 LDS arrays.
//   Phase C: vertical 11-tap conv + SSIM map + block reduction -> atomicAdd.

#define CHN 8
#define HIMG 2048
#define WIMG 2048
#define TH 16
#define TW 64
#define IN_ROWS (TH + 10)   // 26
#define IN_COLS (TW + 10)   // 74
#define IN_STR 76           // padded stride, multiple of 4 floats (16B)

#define C1F 1.0e-4f
#define C2F 9.0e-4f

__device__ __forceinline__ float4 fma4(float s, float4 a, float4 b) {
    return make_float4(fmaf(s, a.x, b.x), fmaf(s, a.y, b.y),
                       fmaf(s, a.z, b.z), fmaf(s, a.w, b.w));
}

__device__ __forceinline__ float ssim1(float mx, float my, float cxx, float cyy, float cxy) {
    float mx2 = mx * mx;
    float my2 = my * my;
    float mxy = mx * my;
    float sx  = cxx - mx2;
    float sy  = cyy - my2;
    float sxy = cxy - mxy;
    float num = (2.0f * mxy + C1F) * (2.0f * sxy + C2F);
    float den = (mx2 + my2 + C1F) * (sx + sy + C2F);
    return num / den;
}

__global__ __launch_bounds__(256)
void ssim_fused(const float* __restrict__ x, const float* __restrict__ y,
                const float* __restrict__ kern, float* __restrict__ out) {
    __shared__ __align__(16) float lx[IN_ROWS][IN_STR];
    __shared__ __align__(16) float ly[IN_ROWS][IN_STR];
    __shared__ __align__(16) float hs[5][IN_ROWS][TW];
    __shared__ float wrs[11], wcs[11];
    __shared__ float wavesum[4];

    const int tid = threadIdx.x;
    const int c0 = blockIdx.x * TW;
    const int r0 = blockIdx.y * TH;
    const size_t chOff = (size_t)blockIdx.z * ((size_t)HIMG * WIMG);
    const float* xp = x + chOff;
    const float* yp = y + chOff;

    // 1D weights from the (separable) 2D kernel, channel 0
    if (tid < 11) {
        wrs[tid] = kern[55 + tid];                 // row 5 (center row)
        wcs[tid] = kern[tid * 11 + 5] / kern[60];  // col 5 / center
    }

    // ---- Phase A: stage inputs (zero-padded halo) ----
    for (int i = tid; i < IN_ROWS * IN_STR; i += 256) {
        int r = i / IN_STR;
        int c = i - r * IN_STR;
        float vx = 0.0f, vy = 0.0f;
        if (c < IN_COLS) {
            int gr = r0 - 5 + r;
            int gc = c0 - 5 + c;
            if ((unsigned)gr < (unsigned)HIMG && (unsigned)gc < (unsigned)WIMG) {
                int gi = gr * WIMG + gc;
                vx = xp[gi];
                vy = yp[gi];
            }
        }
        lx[r][c] = vx;
        ly[r][c] = vy;
    }
    __syncthreads();

    // ---- Phase B: horizontal conv of {x,y,xx,yy,xy} ----
    float wr_[11];
    #pragma unroll
    for (int k = 0; k < 11; k++) wr_[k] = wrs[k];

    for (int j = tid; j < IN_ROWS * 16; j += 256) {   // 26 rows x 16 col-groups
        int r = j >> 4;
        int c = (j & 15) << 2;                        // 0,4,...,60
        float xs[16], ys[16];
        #pragma unroll
        for (int v = 0; v < 4; v++) {
            *reinterpret_cast<float4*>(&xs[4 * v]) =
                *reinterpret_cast<const float4*>(&lx[r][c + 4 * v]);
            *reinterpret_cast<float4*>(&ys[4 * v]) =
                *reinterpret_cast<const float4*>(&ly[r][c + 4 * v]);
        }
        float hx[4], hy[4], hxx[4], hyy[4], hxy[4];
        #pragma unroll
        for (int q = 0; q < 4; q++) {
            float ax = 0.f, ay = 0.f, axx = 0.f, ayy = 0.f, axy = 0.f;
            #pragma unroll
            for (int k = 0; k < 11; k++) {
                float w = wr_[k];
                float xv = xs[q + k];
                float yv = ys[q + k];
                ax  = fmaf(w, xv, ax);
                ay  = fmaf(w, yv, ay);
                axx = fmaf(w, xv * xv, axx);   // CSE dedupes products across q
                ayy = fmaf(w, yv * yv, ayy);
                axy = fmaf(w, xv * yv, axy);
            }
            hx[q] = ax; hy[q] = ay; hxx[q] = axx; hyy[q] = ayy; hxy[q] = axy;
        }
        *reinterpret_cast<float4*>(&hs[0][r][c]) = make_float4(hx[0], hx[1], hx[2], hx[3]);
        *reinterpret_cast<float4*>(&hs[1][r][c]) = make_float4(hy[0], hy[1], hy[2], hy[3]);
        *reinterpret_cast<float4*>(&hs[2][r][c]) = make_float4(hxx[0], hxx[1], hxx[2], hxx[3]);
        *reinterpret_cast<float4*>(&hs[3][r][c]) = make_float4(hyy[0], hyy[1], hyy[2], hyy[3]);
        *reinterpret_cast<float4*>(&hs[4][r][c]) = make_float4(hxy[0], hxy[1], hxy[2], hxy[3]);
    }
    __syncthreads();

    // ---- Phase C: vertical conv + SSIM (4 rows x 4 cols per thread) ----
    float wc_[11];
    #pragma unroll
    for (int k = 0; k < 11; k++) wc_[k] = wcs[k];

    float lsum = 0.0f;
    if (tid < 64) {                 // 16 col-groups x 4 row-groups
        int c = (tid & 15) << 2;
        int rbase = (tid >> 4) << 2;
        float4 acc[4][5];
        #pragma unroll
        for (int o = 0; o < 4; o++)
            #pragma unroll
            for (int a = 0; a < 5; a++)
                acc[o][a] = make_float4(0.f, 0.f, 0.f, 0.f);

        #pragma unroll
        for (int i = 0; i < 14; i++) {
            int hr = rbase + i;     // max 12+13 = 25 = IN_ROWS-1
            float4 h0 = *reinterpret_cast<const float4*>(&hs[0][hr][c]);
            float4 h1 = *reinterpret_cast<const float4*>(&hs[1][hr][c]);
            float4 h2 = *reinterpret_cast<const float4*>(&hs[2][hr][c]);
            float4 h3 = *reinterpret_cast<const float4*>(&hs[3][hr][c]);
            float4 h4 = *reinterpret_cast<const float4*>(&hs[4][hr][c]);
            #pragma unroll
            for (int o = 0; o < 4; o++) {
                int k = i - o;
                if (k >= 0 && k <= 10) {
                    float w = wc_[k];
                    acc[o][0] = fma4(w, h0, acc[o][0]);
                    acc[o][1] = fma4(w, h1, acc[o][1]);
                    acc[o][2] = fma4(w, h2, acc[o][2]);
                    acc[o][3] = fma4(w, h3, acc[o][3]);
                    acc[o][4] = fma4(w, h4, acc[o][4]);
                }
            }
        }
        #pragma unroll
        for (int o = 0; o < 4; o++) {
            lsum += ssim1(acc[o][0].x, acc[o][1].x, acc[o][2].x, acc[o][3].x, acc[o][4].x);
            lsum += ssim1(acc[o][0].y, acc[o][1].y, acc[o][2].y, acc[o][3].y, acc[o][4].y);
            lsum += ssim1(acc[o][0].z, acc[o][1].z, acc[o][2].z, acc[o][3].z, acc[o][4].z);
            lsum += ssim1(acc[o][0].w, acc[o][1].w, acc[o][2].w, acc[o][3].w, acc[o][4].w);
        }
    }

    // ---- block reduction -> one atomic per block ----
    #pragma unroll
    for (int off = 32; off > 0; off >>= 1)
        lsum += __shfl_down(lsum, off, 64);
    if ((tid & 63) == 0) wavesum[tid >> 6] = lsum;
    __syncthreads();
    if (tid == 0) {
        float s = wavesum[0] + wavesum[1] + wavesum[2] + wavesum[3];
        atomicAdd(out, s * (1.0f / 33554432.0f));   // 1/N = 2^-25 exact
    }
}

extern "C" void kernel_launch(void* const* d_in, const int* in_sizes, int n_in,
                              void* d_out, int out_size, void* d_ws, size_t ws_size,
                              hipStream_t stream) {
    const float* x = (const float*)d_in[0];
    const float* y = (const float*)d_in[1];
    const float* k = (const float*)d_in[2];
    float* out = (float*)d_out;

    hipMemsetAsync(d_out, 0, sizeof(float), stream);
    dim3 grid(WIMG / TW, HIMG / TH, CHN);   // 32 x 128 x 8
    ssim_fused<<<grid, 256, 0, stream>>>(x, y, k, out);
}

// Round 2
// 611.197 us; speedup vs baseline: 1.2648x; 1.2648x over previous
//
#include <hip/hip_runtime.h>

// SSIM over (C=8, H=2048, W=2048) fp32, 11x11 separable Gaussian, zero pad.
// Row-streaming separable structure:
//   block = 512-col strip x 86-row chunk, 256 threads, 2 cols/thread.
//   per row: prefetch next row -> write (x,y)-interleaved LDS row (dbuf)
//            -> h-conv of {x,y,xx,yy,xy} in regs (packed f32x2 math)
//            -> vertical 11-slot rotating accumulators -> 1 output row/iter
//            -> SSIM -> per-thread sum; block reduce -> 1 atomicAdd.

typedef float f32x2 __attribute__((ext_vector_type(2)));
typedef float f32x4 __attribute__((ext_vector_type(4)));

#define CHN 8
#define HIMG 2048
#define WIMG 2048
#define SW 512            // strip width = 256 threads * 2 cols
#define CHUNK 86          // output rows per block
#define NCHUNK 24         // 24*86 = 2064 >= 2048 (last chunk clipped)
#define ROWS (CHUNK + 10) // 96 input rows streamed per block
#define LCOLS 528         // LDS cols: global c0-6 .. c0+521 (16B-aligned reads)

#define C1F 1.0e-4f
#define C2F 9.0e-4f

__device__ __forceinline__ float rfl(float v) {
    return __int_as_float(__builtin_amdgcn_readfirstlane(__float_as_int(v)));
}

__global__ __launch_bounds__(256, 3)
void ssim_stream(const float* __restrict__ x, const float* __restrict__ y,
                 const float* __restrict__ kern, float* __restrict__ out)
{
    __shared__ __align__(16) f32x2 rb[2][LCOLS];   // {x,y} per col, double-buffered
    __shared__ float wavesum[4];

    const int t  = threadIdx.x;
    const int c0 = blockIdx.x * SW;
    const int R0 = blockIdx.y * CHUNK;
    const size_t chOff = (size_t)blockIdx.z * (size_t)(HIMG * WIMG);
    const float* xp = x + chOff;
    const float* yp = y + chOff;

    // ---- separable 1-D weights (uniform -> SGPR) ----
    float wr[11], wc[11];
    {
        float kc = rfl(kern[60]);
        #pragma unroll
        for (int k = 0; k < 11; k++) {
            wr[k] = rfl(kern[55 + k]);
            wc[k] = rfl(kern[k * 11 + 5]) / kc;
        }
    }

    // ---- per-thread column geometry ----
    const int gcm = c0 + 2 * t;                 // main col pair (global)
    const bool isL = (t < 3);
    const bool isR = (t >= 3 && t < 8);
    const int Lh  = isL ? (2 * t) : (512 + 2 * t);        // LDS halo slot (even)
    const int gch = isL ? (c0 - 6 + 2 * t) : (c0 + 506 + 2 * t); // global halo col
    const bool hok = isL ? (gch >= 0) : (gch + 1 < WIMG);
    const f32x2 z2 = {0.f, 0.f};

    // ---- row loader (prefetch into regs) ----
    auto loadrow = [&](int gr, f32x2& mx_, f32x2& my_, f32x2& hx_, f32x2& hy_) {
        if ((unsigned)gr < (unsigned)HIMG) {            // uniform branch
            const float* xr = xp + (size_t)gr * WIMG;
            const float* yr = yp + (size_t)gr * WIMG;
            mx_ = *(const f32x2*)(xr + gcm);
            my_ = *(const f32x2*)(yr + gcm);
            if ((isL | isR) && hok) {
                hx_ = *(const f32x2*)(xr + gch);
                hy_ = *(const f32x2*)(yr + gch);
            } else { hx_ = z2; hy_ = z2; }
        } else { mx_ = z2; my_ = z2; hx_ = z2; hy_ = z2; }
    };

    // ---- accumulator slots: 5 arrays x 11 slots x 2 px ----
    f32x2 accM[11][2] = {};   // (mu_x, mu_y)
    f32x2 accQ[11][2] = {};   // (E[xx], E[yy])
    float accXY[11][2] = {};  // E[xy]
    float lsum = 0.f;

    f32x2 cmx, cmy, chx, chy;
    loadrow(R0 - 5, cmx, cmy, chx, chy);

    #pragma unroll 1
    for (int it = 0; it < 9; it++) {          // 9*11 = 99 >= ROWS(96)
        #pragma unroll
        for (int ph = 0; ph < 11; ph++) {
            const int rpc = it * 11 + ph;
            if (rpc < ROWS) {
                const int boff = (rpc & 1) * LCOLS;
                f32x2* b = &rb[0][0] + boff;

                // write current row to LDS (b128, contiguous, conflict-free)
                {
                    f32x4 w; w.x = cmx.x; w.y = cmy.x; w.z = cmx.y; w.w = cmy.y;
                    *(f32x4*)&b[6 + 2 * t] = w;
                    if (isL | isR) {
                        f32x4 h; h.x = chx.x; h.y = chy.x; h.z = chx.y; h.w = chy.y;
                        *(f32x4*)&b[Lh] = h;
                    }
                }
                // prefetch next row (latency hidden under compute)
                f32x2 nmx, nmy, nhx, nhy;
                if (rpc + 1 < ROWS) loadrow(R0 - 5 + rpc + 1, nmx, nmy, nhx, nhy);
                else { nmx = z2; nmy = z2; nhx = z2; nhy = z2; }

                __syncthreads();

                // ---- taps: 14-col window, 7 x ds_read_b128 ----
                f32x4 tp[7];
                #pragma unroll
                for (int j = 0; j < 7; j++) tp[j] = *(const f32x4*)&b[2 * t + 2 * j];
                float xs[14], ys[14];
                #pragma unroll
                for (int j = 0; j < 7; j++) {
                    xs[2*j]   = tp[j].x; ys[2*j]   = tp[j].y;
                    xs[2*j+1] = tp[j].z; ys[2*j+1] = tp[j].w;
                }

                // ---- horizontal 11-tap conv, packed ----
                f32x2 hm[2], hq[2]; float hxy[2];
                #pragma unroll
                for (int p = 0; p < 2; p++) {
                    f32x2 am = z2, aq = z2; float axy = 0.f;
                    #pragma unroll
                    for (int k = 0; k < 11; k++) {
                        const int m = 1 + p + k;
                        f32x2 v = {xs[m], ys[m]};
                        f32x2 w2 = {wr[k], wr[k]};
                        am += w2 * v;            // v_pk_fma_f32
                        aq += w2 * (v * v);      // pk_mul (CSE across p) + pk_fma
                        axy = fmaf(wr[k], xs[m] * ys[m], axy);
                    }
                    hm[p] = am; hq[p] = aq; hxy[p] = axy;
                }

                // ---- vertical: slot s=(ph+j)%11 gets tap wc[10-j]; j=10 births slot ----
                #pragma unroll
                for (int p = 0; p < 2; p++) {
                    #pragma unroll
                    for (int j = 0; j < 11; j++) {
                        const int s = (ph + j) % 11;
                        const float w = wc[10 - j];
                        f32x2 w2 = {w, w};
                        if (j == 10) {
                            accM[s][p] = w2 * hm[p];
                            accQ[s][p] = w2 * hq[p];
                            accXY[s][p] = w * hxy[p];
                        } else {
                            accM[s][p] += w2 * hm[p];
                            accQ[s][p] += w2 * hq[p];
                            accXY[s][p] = fmaf(w, hxy[p], accXY[s][p]);
                        }
                    }
                }

                // ---- finalize slot ph -> output row o = R0 + rpc - 10 ----
                if (rpc >= 10 && (R0 + rpc - 10) < HIMG) {   // uniform
                    #pragma unroll
                    for (int p = 0; p < 2; p++) {
                        float mx = accM[ph][p].x, my = accM[ph][p].y;
                        float cxx = accQ[ph][p].x, cyy = accQ[ph][p].y;
                        float cxy = accXY[ph][p];
                        float mx2 = mx * mx, my2 = my * my, mxy = mx * my;
                        float sx = cxx - mx2, sy = cyy - my2, sxy = cxy - mxy;
                        float num = fmaf(2.f, mxy, C1F) * fmaf(2.f, sxy, C2F);
                        float den = (mx2 + my2 + C1F) * (sx + sy + C2F);
                        lsum += num * __builtin_amdgcn_rcpf(den);
                    }
                }

                cmx = nmx; cmy = nmy; chx = nhx; chy = nhy;
            }
        }
    }

    // ---- block reduction -> one atomic ----
    #pragma unroll
    for (int off = 32; off > 0; off >>= 1)
        lsum += __shfl_down(lsum, off, 64);
    if ((t & 63) == 0) wavesum[t >> 6] = lsum;
    __syncthreads();
    if (t == 0) {
        float s = wavesum[0] + wavesum[1] + wavesum[2] + wavesum[3];
        atomicAdd(out, s * (1.0f / 33554432.0f));   // * 2^-25 (exact)
    }
}

extern "C" void kernel_launch(void* const* d_in, const int* in_sizes, int n_in,
                              void* d_out, int out_size, void* d_ws, size_t ws_size,
                              hipStream_t stream) {
    const float* x = (const float*)d_in[0];
    const float* y = (const float*)d_in[1];
    const float* k = (const float*)d_in[2];
    float* out = (float*)d_out;

    hipMemsetAsync(d_out, 0, sizeof(float), stream);
    dim3 grid(WIMG / SW, NCHUNK, CHN);   // 4 x 24 x 8 = 768 blocks
    ssim_stream<<<grid, 256, 0, stream>>>(x, y, k, out);
}

// Round 7
// 400.768 us; speedup vs baseline: 1.9288x; 1.5251x over previous
//
#include <hip/hip_runtime.h>

// SSIM over (C=8, H=2048, W=2048) fp32, 11x11 separable Gaussian, zero pad.
// Row-streaming separable, 1 px/thread, macro-expanded phases so ALL
// accumulator indices are compile-time constants (round-2 spill fix).
//
//   block = 256-col strip x 128-row chunk, 256 threads, 1 col/thread.
//   per row: write (x,y) row into small dbuf LDS -> h-conv {x,y,xx,yy,xy}
//   in regs (packed f32x2) -> 11 rotating vertical accumulators (static
//   slot idx) -> one finished output row per phase -> SSIM -> local sum.

typedef float f32x2 __attribute__((ext_vector_type(2)));

#define CHN 8
#define HIMG 2048
#define WIMG 2048
#define SW 256
#define CHUNK 128
#define NCHUNK 16
#define ROWS (CHUNK + 10)   // 138 input rows streamed
#define NIT 13              // 13*11 = 143 >= 138
#define LC 268              // LDS cols: global c0-6 .. c0+261

#define C1F 1.0e-4f
#define C2F 9.0e-4f

__device__ __forceinline__ float rfl(float v) {
    return __int_as_float(__builtin_amdgcn_readfirstlane(__float_as_int(v)));
}

// One streamed row. PH = rpc % 11 (compile-time). Slot s=(PH+j)%11 gets
// vertical tap wc[10-j]; j==10 births the slot; slot PH finalizes.
#define PHASE(PHC)                                                          \
  {                                                                         \
    constexpr int PH = (PHC);                                               \
    const int rpc = it * 11 + PH;                                           \
    if (rpc < ROWS) {                                                       \
      float* bx = xrow[rpc & 1];                                            \
      float* by = yrow[rpc & 1];                                            \
      bx[6 + t] = cx;                                                       \
      by[6 + t] = cy;                                                       \
      if (isH) { bx[hslot] = chx; by[hslot] = chy; }                        \
      float nx = 0.f, ny = 0.f, nhx = 0.f, nhy = 0.f;                       \
      {                                                                     \
        const int gr = R0 - 4 + rpc; /* next row's global index */          \
        if (rpc + 1 < ROWS && (unsigned)gr < (unsigned)HIMG) {              \
          const float* xr = xp + (size_t)gr * WIMG;                         \
          const float* yr = yp + (size_t)gr * WIMG;                         \
          nx = xr[gcm]; ny = yr[gcm];                                       \
          if (hok) { nhx = xr[gch]; nhy = yr[gch]; }                        \
        }                                                                   \
      }                                                                     \
      __syncthreads();                                                      \
      f32x2 hm = {0.f, 0.f}, hq = {0.f, 0.f};                               \
      float hxy = 0.f;                                                      \
      _Pragma("unroll")                                                     \
      for (int k = 0; k < 11; k++) {                                        \
        f32x2 v = { bx[t + 1 + k], by[t + 1 + k] };                         \
        f32x2 w2 = { wr[k], wr[k] };                                        \
        hm += w2 * v;                                                       \
        hq += w2 * (v * v);                                                 \
        hxy = fmaf(wr[k], v.x * v.y, hxy);                                  \
      }                                                                     \
      _Pragma("unroll")                                                     \
      for (int j = 0; j < 11; j++) {                                        \
        const int s = (PH + j) % 11;     /* constant after unroll */        \
        const float w = wc[10 - j];                                         \
        f32x2 w2 = { w, w };                                                \
        if (j == 10) {                                                      \
          accM[s] = w2 * hm;                                                \
          accQ[s] = w2 * hq;                                                \
          accXY[s] = w * hxy;                                               \
        } else {                                                            \
          accM[s] += w2 * hm;                                               \
          accQ[s] += w2 * hq;                                               \
          accXY[s] = fmaf(w, hxy, accXY[s]);                                \
        }                                                                   \
      }                                                                     \
      if (rpc >= 10) {                                                      \
        const float mx = accM[PH].x, my = accM[PH].y;                       \
        const float cxx = accQ[PH].x, cyy = accQ[PH].y;                     \
        const float cxy = accXY[PH];                                        \
        const float mx2 = mx * mx, my2 = my * my, mxy = mx * my;            \
        const float sx = cxx - mx2, sy = cyy - my2, sxy = cxy - mxy;        \
        const float num = fmaf(2.f, mxy, C1F) * fmaf(2.f, sxy, C2F);        \
        const float den = (mx2 + my2 + C1F) * (sx + sy + C2F);              \
        lsum += num * __builtin_amdgcn_rcpf(den);                           \
      }                                                                     \
      cx = nx; cy = ny; chx = nhx; chy = nhy;                               \
    }                                                                       \
  }

__global__ __launch_bounds__(256, 4)
void ssim_stream(const float* __restrict__ x, const float* __restrict__ y,
                 const float* __restrict__ kern, float* __restrict__ out)
{
    __shared__ float xrow[2][LC];
    __shared__ float yrow[2][LC];
    __shared__ float wavesum[4];

    const int t  = threadIdx.x;
    const int c0 = blockIdx.x * SW;
    const int R0 = blockIdx.y * CHUNK;
    const size_t chOff = (size_t)blockIdx.z * (size_t)(HIMG * WIMG);
    const float* xp = x + chOff;
    const float* yp = y + chOff;

    // separable 1-D weights (uniform)
    float wr[11], wc[11];
    {
        const float kc = rfl(kern[60]);
        #pragma unroll
        for (int k = 0; k < 11; k++) {
            wr[k] = rfl(kern[55 + k]);
            wc[k] = rfl(kern[k * 11 + 5]) / kc;
        }
    }

    // geometry: main col + (threads 0..11) halo col
    const int gcm = c0 + t;
    const bool isH = (t < 12);
    const int hslot = (t < 6) ? t : (256 + t);            // LDS halo slot
    const int gch  = (t < 6) ? (c0 - 6 + t) : (c0 + 250 + t);
    const bool hok = isH && ((unsigned)gch < (unsigned)WIMG);

    // rotating vertical accumulators (static indexing only!)
    f32x2 accM[11];   // (mu_x, mu_y)
    f32x2 accQ[11];   // (E[xx], E[yy])
    float accXY[11];  // E[xy]
    #pragma unroll
    for (int s = 0; s < 11; s++) {
        accM[s] = {0.f, 0.f}; accQ[s] = {0.f, 0.f}; accXY[s] = 0.f;
    }

    float lsum = 0.f;
    float cx = 0.f, cy = 0.f, chx = 0.f, chy = 0.f;
    {
        const int gr = R0 - 5;                 // first streamed row
        if ((unsigned)gr < (unsigned)HIMG) {
            const float* xr = xp + (size_t)gr * WIMG;
            const float* yr = yp + (size_t)gr * WIMG;
            cx = xr[gcm]; cy = yr[gcm];
            if (hok) { chx = xr[gch]; chy = yr[gch]; }
        }
    }

    #pragma unroll 1
    for (int it = 0; it < NIT; it++) {
        PHASE(0) PHASE(1) PHASE(2) PHASE(3) PHASE(4) PHASE(5)
        PHASE(6) PHASE(7) PHASE(8) PHASE(9) PHASE(10)
    }

    // block reduction -> one atomic
    #pragma unroll
    for (int off = 32; off > 0; off >>= 1)
        lsum += __shfl_down(lsum, off, 64);
    if ((t & 63) == 0) wavesum[t >> 6] = lsum;
    __syncthreads();
    if (t == 0) {
        const float s = wavesum[0] + wavesum[1] + wavesum[2] + wavesum[3];
        atomicAdd(out, s * (1.0f / 33554432.0f));   // * 2^-25 (exact)
    }
}

extern "C" void kernel_launch(void* const* d_in, const int* in_sizes, int n_in,
                              void* d_out, int out_size, void* d_ws, size_t ws_size,
                              hipStream_t stream) {
    const float* x = (const float*)d_in[0];
    const float* y = (const float*)d_in[1];
    const float* k = (const float*)d_in[2];
    float* out = (float*)d_out;

    hipMemsetAsync(d_out, 0, sizeof(float), stream);
    dim3 grid(WIMG / SW, NCHUNK, CHN);   // 8 x 16 x 8 = 1024 blocks
    ssim_stream<<<grid, 256, 0, stream>>>(x, y, k, out);
}